// Round 1
// 102.823 us; speedup vs baseline: 1.0110x; 1.0110x over previous
//
#include <hip/hip_runtime.h>
#include <hip/hip_bf16.h>

__device__ float g_pre_static[8 * 1024 * 1024];  // fallback scratch (32 MB)

__device__ __forceinline__ float rcp_(float x)   { return __builtin_amdgcn_rcpf(x); }
__device__ __forceinline__ float sigm_f(float x) { return rcp_(1.0f + __expf(-x)); }
__device__ __forceinline__ float tanh_f(float x) { return 1.0f - 2.0f*rcp_(__expf(2.0f*x) + 1.0f); }
__device__ __forceinline__ float sigm(float x)  { return 1.0f/(1.0f + __expf(-x)); }
__device__ __forceinline__ float tanh_(float x) { float e = __expf(2.0f*x); return (e-1.0f)/(e+1.0f); }

// DPP move within 16-lane rows: pure VALU, no lgkmcnt wait (vs ds_bpermute).
// SEMANTICS (verified R11/R12): row_shr:k / row_ror:k deliver to lane i the
// value from lane i-k (mod 16 for ror) — data moves toward HIGHER lanes.
template<int CTRL>
__device__ __forceinline__ float dppf(float x) {
    return __int_as_float(__builtin_amdgcn_update_dpp(
        0, __float_as_int(x), CTRL, 0xF, 0xF, true));
}
// CTRL: row_shr:k = 0x110+k ; row_ror:k = 0x120+k

// ---------------------------------------------------------------------------
// FUSED kernel, H == 8, ID == 64 (compile-time), S <= 64.
// One block per 4 batches, 512 threads (8 waves).
// Phase 1 (all 8 waves): stage x rows (LDS) + pre-GEMM into LDS ps[t][b4][32]
//   with the gate-pair interleaved column layout l = gp*16 + w*2 + e,
//   gate g = 2*gp + e (matches the DPP recurrence's read pattern).
// Phase 2 (wave 0 only): the validated DPP recurrence, pre sourced from LDS
//   (64-lane read covers each bank exactly 2x -> conflict-free; ~64cy latency
//   hidden by 1-deep prefetch under the ~200cy per-t dependency chain).
// This removes the pre round-trip through HBM/L3 (4 MB), one dispatch, and
// the cross-XCD load-latency exposure of the old k_rec8 prefetch.
template<int IDD>
__global__ __launch_bounds__(512) void k_fused8(
    const float* __restrict__ x_,
    const float* __restrict__ W0, const float* __restrict__ b0p, const float* __restrict__ q0v,
    const float* __restrict__ W1, const float* __restrict__ b1p, const float* __restrict__ q1v,
    const float* __restrict__ W2, const float* __restrict__ b2p, const float* __restrict__ q2v,
    const float* __restrict__ W3, const float* __restrict__ b3p, const float* __restrict__ q3v,
    float* __restrict__ out, int S, int B)
{
    constexpr int DIN  = IDD + 8;
    constexpr int SMAX = 64;
    constexpr int TCH  = 32;                 // t-chunk for x staging
    __shared__ float xs[4][TCH][IDD];        // 32 KB
    __shared__ float ps[SMAX][4][32];        // 32 KB  (pre, interleaved cols)

    const int tid = threadIdx.x;
    const long b0 = (long)blockIdx.x * 4;
    const float* Wp[4] = {W0, W1, W2, W3};
    const float* bp[4] = {b0p, b1p, b2p, b3p};
    const float* qp[4] = {q0v, q1v, q2v, q3v};

    // ---- per-thread GEMM identity ----
    const int l  = tid & 31;                 // interleaved output column
    const int b4 = (tid >> 5) & 3;           // local batch
    const int hh = tid >> 7;                 // 0..3: t-subrange within chunk
    const int gp = l >> 4, w8 = (l >> 1) & 7, e = l & 1;
    const int g  = 2*gp + e;

    // my W row into registers (L1/L2-hot: W is 9 KB total)
    float wr[IDD];
    {
        const float4* wv = (const float4*)(Wp[g] + (long)w8*DIN);
        #pragma unroll
        for (int k4 = 0; k4 < IDD/4; ++k4) {
            float4 v = wv[k4];
            wr[4*k4] = v.x; wr[4*k4+1] = v.y; wr[4*k4+2] = v.z; wr[4*k4+3] = v.w;
        }
    }
    const float bias = bp[g][w8];

    // ---- chunked stage + GEMM ----
    for (int c = 0; c < S; c += TCH) {
        // stage x: 4 batches x TCH timesteps x IDD floats (coalesced float4)
        {
            const int nf4 = 4 * TCH * (IDD/4);      // 2048 for IDD=64
            for (int idx = tid; idx < nf4; idx += 512) {
                int k4 = idx & (IDD/4 - 1);
                int r  = idx >> 4;                  // r = b4s*TCH + tl
                int bs = r >> 5;                    // TCH==32
                int tl = r & (TCH - 1);
                int t  = c + tl; if (t >= S) t = S - 1;
                long bb = b0 + bs; if (bb >= B) bb = B - 1;
                float4 v = ((const float4*)(x_ + ((long)t*B + bb)*IDD))[k4];
                ((float4*)&xs[bs][tl][0])[k4] = v;
            }
        }
        __syncthreads();
        // GEMM this chunk: each thread does 8 timesteps for its (b4, l)
        #pragma unroll
        for (int i = 0; i < TCH/4; ++i) {
            int t = c + hh*(TCH/4) + i;
            if (t < S) {
                const float4* xv = (const float4*)&xs[b4][t - c][0];
                float a0 = bias, a1 = 0.0f, a2 = 0.0f, a3 = 0.0f;
                #pragma unroll
                for (int k4 = 0; k4 < IDD/4; ++k4) {
                    float4 v = xv[k4];               // broadcast within lanes
                    a0 = fmaf(wr[4*k4],   v.x, a0);
                    a1 = fmaf(wr[4*k4+1], v.y, a1);
                    a2 = fmaf(wr[4*k4+2], v.z, a2);
                    a3 = fmaf(wr[4*k4+3], v.w, a3);
                }
                ps[t][b4][l] = (a0 + a1) + (a2 + a3);
            }
        }
        __syncthreads();      // protect xs before next chunk / ps before rec
    }

    if (tid >= 64) return;    // waves 1..7 done; wave 0 runs the recurrence

    // ---- recurrence (validated DPP structure from k_rec8, pre from LDS) ----
    const int lane = tid;
    const int w    = lane & 7;
    const int gpr  = (lane >> 3) & 1;
    const long b   = b0 + (lane >> 4);
    const int g0 = 2*gpr, g1 = 2*gpr + 1;

    // rotated hidden-weight rows matching ror:k's hx_{(w-k)&7}
    float wrot0[8], wrot1[8];
    #pragma unroll
    for (int k = 0; k < 8; ++k) {
        int j = (w - k) & 7;
        wrot0[k] = Wp[g0][(long)w*DIN + IDD + j];
        wrot1[k] = Wp[g1][(long)w*DIN + IDD + j];
    }
    const float qv0 = qp[g0][w], qv1 = qp[g1][w];
    const float mult0 = (w < 7) ? __cosf(qv0) : 1.0f;
    const float mult1 = (w < 7) ? __cosf(qv1) : 1.0f;
    const float qadd0 = (w == 7) ? qv0 : 0.0f;
    const float qadd1 = (w == 7) ? qv1 : 0.0f;
    const float ascl = gpr ? 2.0f : 1.0f;   // gate 2: tanh = 2*sigm(2x)-1
    const float aoff = gpr ? -1.0f : 0.0f;

    float cxw = 0.0f, hxw = 0.0f;
    float hxr[8];
    #pragma unroll
    for (int k = 0; k < 8; ++k) hxr[k] = 0.0f;

    // LDS float2 base: ps[t][b4][gpr*16 + 2w]; stride 64 float2 per t
    const float2* pbase = (const float2*)(&ps[0][lane >> 4][gpr*16 + 2*w]);

    float2 pn = pbase[0];
    #pragma unroll 2
    for (int t = 0; t < S; ++t) {
        float2 pc = pn;                      // loaded >=1 full chain ago
        int tn = (t + 1 < S) ? (t + 1) : (S - 1);
        pn = pbase[(long)tn * 64];           // issue next-t ds_read now

        // th = pre + Wh.hx  — two 4-deep chains + combine (shorter latency)
        float tA0 = pc.x, tA1 = pc.y, tB0, tB1;
        tA0 = fmaf(wrot0[0], hxr[0], tA0);  tA1 = fmaf(wrot1[0], hxr[0], tA1);
        tA0 = fmaf(wrot0[1], hxr[1], tA0);  tA1 = fmaf(wrot1[1], hxr[1], tA1);
        tA0 = fmaf(wrot0[2], hxr[2], tA0);  tA1 = fmaf(wrot1[2], hxr[2], tA1);
        tA0 = fmaf(wrot0[3], hxr[3], tA0);  tA1 = fmaf(wrot1[3], hxr[3], tA1);
        tB0 = wrot0[4]*hxr[4];              tB1 = wrot1[4]*hxr[4];
        tB0 = fmaf(wrot0[5], hxr[5], tB0);  tB1 = fmaf(wrot1[5], hxr[5], tB1);
        tB0 = fmaf(wrot0[6], hxr[6], tB0);  tB1 = fmaf(wrot1[6], hxr[6], tB1);
        tB0 = fmaf(wrot0[7], hxr[7], tB0);  tB1 = fmaf(wrot1[7], hxr[7], tB1);
        float th0 = tA0 + tB0;
        float th1 = tA1 + tB1;

        float P0 = __cosf(th0 + qadd0);
        float P1 = __cosf(th1 + qadd1);

        // inclusive prefix product over the 8 wires (DPP scan)
        float s;
        s = dppf<0x111>(P0); P0 *= (w >= 1) ? s : 1.0f;
        s = dppf<0x111>(P1); P1 *= (w >= 1) ? s : 1.0f;
        s = dppf<0x112>(P0); P0 *= (w >= 2) ? s : 1.0f;
        s = dppf<0x112>(P1); P1 *= (w >= 2) ? s : 1.0f;
        s = dppf<0x114>(P0); P0 *= (w >= 4) ? s : 1.0f;
        s = dppf<0x114>(P1); P1 *= (w >= 4) ? s : 1.0f;

        float act0 = ascl * sigm_f(ascl * (mult0 * P0)) + aoff;
        float act1 = sigm_f(mult1 * P1);

        // swap gate-pairs across octets (same wire): row_ror:8
        float ex0 = dppf<0x128>(act0);
        float ex1 = dppf<0x128>(act1);
        float fv = gpr ? ex0  : act0;
        float iv = gpr ? ex1  : act1;
        float gv = gpr ? act0 : ex0;
        float ov = gpr ? act1 : ex1;

        cxw = fv*cxw + iv*gv;
        hxw = ov * tanh_f(cxw);

        if (gpr == 0 && b < B) out[((long)t*B + b)*8 + w] = hxw;

        // hx all-gather: hxr[k] = hx_{(w-k)&7} via row_ror:k
        hxr[0] = hxw;
        hxr[1] = dppf<0x121>(hxw);
        hxr[2] = dppf<0x122>(hxw);
        hxr[3] = dppf<0x123>(hxw);
        hxr[4] = dppf<0x124>(hxw);
        hxr[5] = dppf<0x125>(hxw);
        hxr[6] = dppf<0x126>(hxw);
        hxr[7] = dppf<0x127>(hxw);
    }

    if (gpr == 0 && b < B) {
        out[((long)S*B + b)*8 + w]     = hxw;
        out[((long)S*B + B + b)*8 + w] = cxw;
    }
}

// ---------------------------------------------------------------------------
// Specialized pre-GEMM (kept as fallback for S > 64), H == 8.
template<int IDD>
__global__ __launch_bounds__(256) void k_pre8(
    const float* __restrict__ x_,
    const float* __restrict__ W0, const float* __restrict__ b0p,
    const float* __restrict__ W1, const float* __restrict__ b1p,
    const float* __restrict__ W2, const float* __restrict__ b2p,
    const float* __restrict__ W3, const float* __restrict__ b3p,
    float* __restrict__ pre, int S, int B)
{
    constexpr int DIN = IDD + 8;
    __shared__ float xs[8][IDD];
    const int t   = blockIdx.x;
    const int tid = threadIdx.x;
    const int bl  = tid >> 5;
    const int l   = tid & 31;
    const int gp  = l >> 4, w = (l >> 1) & 7, e = l & 1;
    const int g   = 2*gp + e;
    const long b0 = (long)blockIdx.y * 8;
    const float* Wp[4] = {W0, W1, W2, W3};
    const float* bp[4] = {b0p, b1p, b2p, b3p};

    if (tid < 8*(IDD/4)) {
        int r = tid / (IDD/4), k4 = tid % (IDD/4);
        long bb = b0 + r; if (bb >= B) bb = B - 1;
        float4 v = ((const float4*)(x_ + ((long)t*B + bb)*IDD))[k4];
        ((float4*)&xs[r][0])[k4] = v;
    }

    float wr[IDD];
    {
        const float4* wv = (const float4*)(Wp[g] + (long)w*DIN);
        #pragma unroll
        for (int k4 = 0; k4 < IDD/4; ++k4) {
            float4 v = wv[k4];
            wr[4*k4] = v.x; wr[4*k4+1] = v.y; wr[4*k4+2] = v.z; wr[4*k4+3] = v.w;
        }
    }
    float a = bp[g][w];
    __syncthreads();

    const long b = b0 + bl;
    if (b >= B) return;
    const float4* xv = (const float4*)&xs[bl][0];
    #pragma unroll
    for (int k4 = 0; k4 < IDD/4; ++k4) {
        float4 v = xv[k4];
        a += wr[4*k4]*v.x + wr[4*k4+1]*v.y + wr[4*k4+2]*v.z + wr[4*k4+3]*v.w;
    }
    pre[((long)t*B + b)*32 + l] = a;
}

// ---------------------------------------------------------------------------
// Generic pre-GEMM fallback (runtime ID/H), f32 inputs, OLD layout
__global__ __launch_bounds__(256) void k_pre_gen(
    const float* __restrict__ x_,
    const float* W0, const float* b0p,
    const float* W1, const float* b1p,
    const float* W2, const float* b2p,
    const float* W3, const float* b3p,
    float* __restrict__ pre,
    int S, int B, int ID, int H, int SP)
{
    extern __shared__ float lds[];
    const int dIn  = ID + H;
    const int dInP = dIn + 1;
    float* xs    = lds;
    float* wsh   = lds + 64*SP;
    float* sbias = wsh + 4*H*dInP;
    const int t   = blockIdx.x;
    const int tid = threadIdx.x;
    const int bl  = tid & 63;
    const int q   = tid >> 6;
    const int b0  = blockIdx.y * 64;
    const float* Wp[4] = {W0, W1, W2, W3};
    const float* bp[4] = {b0p, b1p, b2p, b3p};

    for (int g = 0; g < 4; ++g)
        for (int idx = tid; idx < H*dIn; idx += 256) {
            int w = idx / dIn, k = idx - w*dIn;
            wsh[(g*H + w)*dInP + k] = Wp[g][idx];
        }
    for (int idx = tid; idx < 4*H; idx += 256)
        sbias[idx] = bp[idx / H][idx % H];

    {
        int total = 64 * ID;
        for (int i = tid; i < total; i += 256) {
            int r = i / ID, c = i - r*ID;
            long bb = (long)b0 + r; if (bb >= B) bb = B - 1;
            xs[r*SP + c] = x_[((long)t*B + bb)*ID + c];
        }
    }
    __syncthreads();

    const int b = b0 + bl;
    if (b < B) {
        const float* xrow = &xs[bl*SP];
        float* orow = pre + (((long)t*B + b)*4 + q)*H;
        for (int w = 0; w < H; ++w) {
            float acc = sbias[q*H + w];
            const float* wrow = &wsh[(q*H + w)*dInP];
            for (int k = 0; k < ID; ++k) acc += xrow[k] * wrow[k];
            orow[w] = acc;
        }
    }
}

// ---------------------------------------------------------------------------
// Recurrence, H==8/ID==64 fast path (fallback for S > 64).
__global__ __launch_bounds__(64) void k_rec8(
    const float* __restrict__ W0, const float* __restrict__ q0,
    const float* __restrict__ W1, const float* __restrict__ q1,
    const float* __restrict__ W2, const float* __restrict__ q2,
    const float* __restrict__ W3, const float* __restrict__ q3,
    const float* __restrict__ pre,
    float* __restrict__ out, int S, int B, int ID)
{
    const int dIn  = ID + 8;
    const int lane = threadIdx.x;
    const int w    = lane & 7;
    const int gp   = (lane >> 3) & 1;
    const int b    = blockIdx.x*4 + (lane >> 4);
    const int bs   = (b < B) ? b : (B - 1);
    const float* Wp[4] = {W0, W1, W2, W3};
    const float* qp[4] = {q0, q1, q2, q3};
    const int g0 = 2*gp, g1 = 2*gp + 1;

    float wrot0[8], wrot1[8];
    #pragma unroll
    for (int k = 0; k < 8; ++k) {
        int j = (w - k) & 7;
        wrot0[k] = Wp[g0][(long)w*dIn + ID + j];
        wrot1[k] = Wp[g1][(long)w*dIn + ID + j];
    }
    const float qv0 = qp[g0][w], qv1 = qp[g1][w];
    const float mult0 = (w < 7) ? __cosf(qv0) : 1.0f;
    const float mult1 = (w < 7) ? __cosf(qv1) : 1.0f;
    const float qadd0 = (w == 7) ? qv0 : 0.0f;
    const float qadd1 = (w == 7) ? qv1 : 0.0f;
    const float ascl = gp ? 2.0f : 1.0f;
    const float aoff = gp ? -1.0f : 0.0f;

    float cxw = 0.0f, hxw = 0.0f;
    float hxr[8];
    #pragma unroll
    for (int k = 0; k < 8; ++k) hxr[k] = 0.0f;

    const float2* base = (const float2*)(pre + (long)bs*32 + gp*16 + 2*w);
    const long tstep = (long)B*16;

    float2 pf[4];
    #pragma unroll
    for (int d = 0; d < 4; ++d) {
        int tt = (d < S) ? d : (S - 1);
        pf[d] = base[(long)tt*tstep];
    }

    for (int t0 = 0; t0 < S; t0 += 4) {
        #pragma unroll
        for (int d = 0; d < 4; ++d) {
            const int t = t0 + d;
            if (t < S) {
                float2 pc = pf[d];
                int tn = t + 4; if (tn >= S) tn = S - 1;
                pf[d] = base[(long)tn*tstep];

                float th0 = pc.x, th1 = pc.y;
                #pragma unroll
                for (int k = 0; k < 8; ++k) {
                    th0 = fmaf(wrot0[k], hxr[k], th0);
                    th1 = fmaf(wrot1[k], hxr[k], th1);
                }
                float P0 = __cosf(th0 + qadd0);
                float P1 = __cosf(th1 + qadd1);

                float s;
                s = dppf<0x111>(P0); P0 *= (w >= 1) ? s : 1.0f;
                s = dppf<0x111>(P1); P1 *= (w >= 1) ? s : 1.0f;
                s = dppf<0x112>(P0); P0 *= (w >= 2) ? s : 1.0f;
                s = dppf<0x112>(P1); P1 *= (w >= 2) ? s : 1.0f;
                s = dppf<0x114>(P0); P0 *= (w >= 4) ? s : 1.0f;
                s = dppf<0x114>(P1); P1 *= (w >= 4) ? s : 1.0f;

                float act0 = ascl * sigm_f(ascl * (mult0 * P0)) + aoff;
                float act1 = sigm_f(mult1 * P1);

                float ex0 = dppf<0x128>(act0);
                float ex1 = dppf<0x128>(act1);
                float fv = gp ? ex0  : act0;
                float iv = gp ? ex1  : act1;
                float gv = gp ? act0 : ex0;
                float ov = gp ? act1 : ex1;

                cxw = fv*cxw + iv*gv;
                hxw = ov * tanh_f(cxw);

                if (gp == 0 && b < B) out[((long)t*B + b)*8 + w] = hxw;

                hxr[0] = hxw;
                hxr[1] = dppf<0x121>(hxw);
                hxr[2] = dppf<0x122>(hxw);
                hxr[3] = dppf<0x123>(hxw);
                hxr[4] = dppf<0x124>(hxw);
                hxr[5] = dppf<0x125>(hxw);
                hxr[6] = dppf<0x126>(hxw);
                hxr[7] = dppf<0x127>(hxw);
            }
        }
    }

    if (gp == 0 && b < B) {
        out[((long)S*B + b)*8 + w]     = hxw;
        out[((long)S*B + B + b)*8 + w] = cxw;
    }
}

// ---------------------------------------------------------------------------
// Generic runtime-H recurrence fallback (H <= 32), f32, OLD pre layout.
__global__ __launch_bounds__(64) void k_rec_g(
    const float* __restrict__ pre,
    const float* W0, const float* q0,
    const float* W1, const float* q1,
    const float* W2, const float* q2,
    const float* W3, const float* q3,
    float* __restrict__ out, int S, int B, int ID, int H)
{
    __shared__ float sWh[4*32*32];
    __shared__ float scq[4*32];
    const int dIn = ID + H;
    const int tid = threadIdx.x;
    const int b   = blockIdx.x*64 + tid;
    const float* Wp[4] = {W0, W1, W2, W3};
    const float* qp[4] = {q0, q1, q2, q3};

    for (int idx = tid; idx < 4*H*H; idx += 64) {
        int g = idx / (H*H), r = idx % (H*H);
        int w = r / H, j = r % H;
        sWh[(g*H + w)*H + j] = Wp[g][(long)w*dIn + ID + j];
    }
    for (int idx = tid; idx < 4*H; idx += 64) {
        int g = idx / H, w = idx % H;
        float qv = qp[g][w];
        scq[idx] = (w < H-1) ? __cosf(qv) : qv;
    }
    __syncthreads();
    if (b >= B) return;

    float hx[32], cx[32], gate[4][32], th[32];
    for (int w = 0; w < H; ++w) { hx[w] = 0.0f; cx[w] = 0.0f; }

    for (int t = 0; t < S; ++t) {
        const float* pt = pre + ((long)t*B + b)*4*H;
        for (int g = 0; g < 4; ++g) {
            for (int w = 0; w < H; ++w) {
                float a = pt[g*H + w];
                const float* wrp = &sWh[(g*H + w)*H];
                for (int j = 0; j < H; ++j) a += wrp[j]*hx[j];
                th[w] = a;
            }
            float cum = 1.0f;
            for (int w = 0; w < H-1; ++w) {
                cum *= __cosf(th[w]);
                gate[g][w] = scq[g*H + w] * cum;
            }
            gate[g][H-1] = cum * __cosf(th[H-1] + scq[g*H + H-1]);
        }
        float* orow = out + ((long)t*B + b)*H;
        for (int w = 0; w < H; ++w) {
            float fv = sigm (gate[0][w]);
            float iv = sigm (gate[1][w]);
            float gv = tanh_(gate[2][w]);
            float ov = sigm (gate[3][w]);
            cx[w] = fv*cx[w] + iv*gv;
            hx[w] = ov*tanh_(cx[w]);
            orow[w] = hx[w];
        }
    }
    float* oh = out + ((long)S*B + b)*H;
    float* oc = out + ((long)S*B + B + b)*H;
    for (int w = 0; w < H; ++w) { oh[w] = hx[w]; oc[w] = cx[w]; }
}

static bool derive(long sz[13], long osz, long& S, long& B, long& ID, long& H) {
    H = sz[3];
    long dIn = (H > 0) ? sz[1] / H : 0;
    ID = dIn - H;
    long TB = (ID > 0) ? sz[0] / ID : 0;
    B = (H > 0) ? (osz / H - TB) / 2 : 0;
    S = (B > 0) ? TB / B : 0;
    return (H >= 1 && H <= 32 && ID >= 1 && B >= 1 && S >= 1 &&
            S*B == TB && (S*B + 2*B)*H == osz &&
            dIn*H == sz[1] && TB*ID == sz[0]);
}

extern "C" void kernel_launch(void* const* d_in, const int* in_sizes, int n_in,
                              void* d_out, int out_size, void* d_ws, size_t ws_size,
                              hipStream_t stream) {
    const float* x  = (const float*)d_in[0];
    const float* Wf = (const float*)d_in[1];  const float* bfv = (const float*)d_in[2];  const float* qf = (const float*)d_in[3];
    const float* Wi = (const float*)d_in[4];  const float* biv = (const float*)d_in[5];  const float* qi = (const float*)d_in[6];
    const float* Wg = (const float*)d_in[7];  const float* bgv = (const float*)d_in[8];  const float* qg = (const float*)d_in[9];
    const float* Wo = (const float*)d_in[10]; const float* bov = (const float*)d_in[11]; const float* qo = (const float*)d_in[12];
    float* out = (float*)d_out;

    long S = 0, B = 0, ID = 0, H = 0;
    bool ok = false;
    for (int scale : {1, 4, 2}) {
        long sz[13];
        for (int i = 0; i < 13; ++i) sz[i] = (long)in_sizes[i] / scale;
        long osz = (long)out_size / scale;
        if (derive(sz, osz, S, B, ID, H)) { ok = true; break; }
    }
    if (!ok) { H = 8; ID = 64; B = 256; S = 64; }
    long dIn = ID + H;

    if (H == 8 && ID == 64 && S <= 64) {
        // fully fused: no intermediate pre buffer, single dispatch
        k_fused8<64><<<dim3((unsigned)((B + 3) / 4)), dim3(512), 0, stream>>>(
            x, Wf, bfv, qf, Wi, biv, qi, Wg, bgv, qg, Wo, bov, qo,
            out, (int)S, (int)B);
        return;
    }

    size_t pre_bytes = (size_t)S * 4 * H * B * sizeof(float);
    float* pre = (ws_size >= pre_bytes) ? (float*)d_ws : g_pre_static;

    if (H == 8 && ID == 64) {
        k_pre8<64><<<dim3((unsigned)S, (unsigned)((B + 7) / 8)), dim3(256), 0, stream>>>(
            x, Wf, bfv, Wi, biv, Wg, bgv, Wo, bov, pre, (int)S, (int)B);
        k_rec8<<<dim3((unsigned)((B + 3) / 4)), dim3(64), 0, stream>>>(
            Wf, qf, Wi, qi, Wg, qg, Wo, qo, pre, out, (int)S, (int)B, (int)ID);
    } else {
        int SP = (int)ID + 1;
        size_t lds_bytes = (size_t)(64*SP + 4*H*(dIn + 1) + 4*H) * sizeof(float);
        k_pre_gen<<<dim3((unsigned)S, (unsigned)((B + 63) / 64)), dim3(256), lds_bytes, stream>>>(
            x, Wf, bfv, Wi, biv, Wg, bgv, Wo, bov, pre,
            (int)S, (int)B, (int)ID, (int)H, SP);
        k_rec_g<<<dim3((unsigned)((B + 63) / 64)), dim3(64), 0, stream>>>(
            pre, Wf, qf, Wi, qi, Wg, qg, Wo, qo, out, (int)S, (int)B, (int)ID, (int)H);
    }
}

// Round 2
// 100.333 us; speedup vs baseline: 1.0361x; 1.0248x over previous
//
#include <hip/hip_runtime.h>
#include <hip/hip_bf16.h>

__device__ float g_pre_static[8 * 1024 * 1024];  // fallback scratch (32 MB)

__device__ __forceinline__ float rcp_(float x)   { return __builtin_amdgcn_rcpf(x); }
__device__ __forceinline__ float sigm_f(float x) { return rcp_(1.0f + __expf(-x)); }
__device__ __forceinline__ float tanh_f(float x) { return 1.0f - 2.0f*rcp_(__expf(2.0f*x) + 1.0f); }
__device__ __forceinline__ float sigm(float x)  { return 1.0f/(1.0f + __expf(-x)); }
__device__ __forceinline__ float tanh_(float x) { float e = __expf(2.0f*x); return (e-1.0f)/(e+1.0f); }

// DPP move within 16-lane rows: pure VALU, no lgkmcnt wait (vs ds_bpermute).
// SEMANTICS (verified R11/R12): row_shr:k / row_ror:k deliver to lane i the
// value from lane i-k (mod 16 for ror) — data moves toward HIGHER lanes.
template<int CTRL>
__device__ __forceinline__ float dppf(float x) {
    return __int_as_float(__builtin_amdgcn_update_dpp(
        0, __float_as_int(x), CTRL, 0xF, 0xF, true));
}
// CTRL: row_shr:k = 0x110+k ; row_ror:k = 0x120+k

// ---------------------------------------------------------------------------
// FUSED kernel, H == 8, ID == 64 (compile-time), S <= 64.
// One block per 4 batches, 576 threads (9 waves).
//   waves 0..7 : stage x (LDS) + pre-GEMM chunk c into ps[t][b4][32]
//   wave  8    : validated DPP recurrence, lagging ONE chunk behind.
// Uniform __syncthreads per chunk; rec reads ps of chunk c-1 (completed
// before the previous barrier) while waves 0..7 produce chunk c -> the
// GEMM is off the critical path except for the first chunk.
// Rec prefetch is clamped to the chunk, so it never reads the chunk
// currently being written.
template<int IDD>
__global__ __launch_bounds__(576) void k_fused8(
    const float* __restrict__ x_,
    const float* __restrict__ W0, const float* __restrict__ b0p, const float* __restrict__ q0v,
    const float* __restrict__ W1, const float* __restrict__ b1p, const float* __restrict__ q1v,
    const float* __restrict__ W2, const float* __restrict__ b2p, const float* __restrict__ q2v,
    const float* __restrict__ W3, const float* __restrict__ b3p, const float* __restrict__ q3v,
    float* __restrict__ out, int S, int B)
{
    constexpr int DIN  = IDD + 8;
    constexpr int SMAX = 64;
    constexpr int TCH  = 16;                 // t-chunk (4 chunks for S=64)
    __shared__ float xs[4][TCH][IDD];        // 16 KB
    __shared__ float ps[SMAX][4][32];        // 32 KB  (pre, interleaved cols)

    const int tid = threadIdx.x;
    const long b0 = (long)blockIdx.x * 4;
    const float* Wp[4] = {W0, W1, W2, W3};
    const float* bp[4] = {b0p, b1p, b2p, b3p};
    const float* qp[4] = {q0v, q1v, q2v, q3v};

    // ---- GEMM identity (threads 0..511) ----
    const int l   = tid & 31;                // interleaved output column
    const int b4g = (tid >> 5) & 3;          // local batch
    const int sub = (tid >> 7) & 3;          // t-subrange within chunk
    const int gp  = l >> 4, w8 = (l >> 1) & 7, e = l & 1;
    const int g   = 2*gp + e;

    float wr[IDD];
    float bias = 0.0f;
    if (tid < 512) {                          // W row into registers (L1-hot)
        const float4* wv = (const float4*)(Wp[g] + (long)w8*DIN);
        #pragma unroll
        for (int k4 = 0; k4 < IDD/4; ++k4) {
            float4 v = wv[k4];
            wr[4*k4] = v.x; wr[4*k4+1] = v.y; wr[4*k4+2] = v.z; wr[4*k4+3] = v.w;
        }
        bias = bp[g][w8];
    }

    // ---- recurrence identity (threads 512..575, one wave) ----
    const int lane = tid & 63;
    const int w    = lane & 7;
    const int gpr  = (lane >> 3) & 1;
    const long bb_ = b0 + (lane >> 4);
    const int g0 = 2*gpr, g1 = 2*gpr + 1;

    float wrot0[8], wrot1[8];
    float mult0 = 1.0f, mult1 = 1.0f, qadd0 = 0.0f, qadd1 = 0.0f;
    if (tid >= 512) {
        #pragma unroll
        for (int k = 0; k < 8; ++k) {        // rotated rows match ror:k gather
            int j = (w - k) & 7;
            wrot0[k] = Wp[g0][(long)w*DIN + IDD + j];
            wrot1[k] = Wp[g1][(long)w*DIN + IDD + j];
        }
        float qv0 = qp[g0][w], qv1 = qp[g1][w];
        mult0 = (w < 7) ? __cosf(qv0) : 1.0f;
        mult1 = (w < 7) ? __cosf(qv1) : 1.0f;
        qadd0 = (w == 7) ? qv0 : 0.0f;
        qadd1 = (w == 7) ? qv1 : 0.0f;
    }
    const float ascl = gpr ? 2.0f : 1.0f;    // gate 2: tanh = 2*sigm(2x)-1
    const float aoff = gpr ? -1.0f : 0.0f;

    float cxw = 0.0f, hxw = 0.0f;
    float hxr[8];
    #pragma unroll
    for (int k = 0; k < 8; ++k) hxr[k] = 0.0f;

    // LDS float2 base: ps[t][b4][gpr*16 + 2w]; stride 64 float2 per t
    const float2* pbase = (const float2*)(&ps[0][lane >> 4][gpr*16 + 2*w]);

    // recurrence over [t0e, t1e) — prefetch clamped inside the range
    auto rec_run = [&](int t0e, int t1e) {
        float2 pn = pbase[(long)t0e * 64];
        for (int t = t0e; t < t1e; ++t) {
            float2 pc = pn;                  // loaded >= 1 chain ago
            int tn = (t + 1 < t1e) ? (t + 1) : t;
            pn = pbase[(long)tn * 64];       // issue next ds_read, no wait

            // th = pre + Wh.hx — two 4-deep chains + combine
            float tA0 = pc.x, tA1 = pc.y, tB0, tB1;
            tA0 = fmaf(wrot0[0], hxr[0], tA0);  tA1 = fmaf(wrot1[0], hxr[0], tA1);
            tA0 = fmaf(wrot0[1], hxr[1], tA0);  tA1 = fmaf(wrot1[1], hxr[1], tA1);
            tA0 = fmaf(wrot0[2], hxr[2], tA0);  tA1 = fmaf(wrot1[2], hxr[2], tA1);
            tA0 = fmaf(wrot0[3], hxr[3], tA0);  tA1 = fmaf(wrot1[3], hxr[3], tA1);
            tB0 = wrot0[4]*hxr[4];              tB1 = wrot1[4]*hxr[4];
            tB0 = fmaf(wrot0[5], hxr[5], tB0);  tB1 = fmaf(wrot1[5], hxr[5], tB1);
            tB0 = fmaf(wrot0[6], hxr[6], tB0);  tB1 = fmaf(wrot1[6], hxr[6], tB1);
            tB0 = fmaf(wrot0[7], hxr[7], tB0);  tB1 = fmaf(wrot1[7], hxr[7], tB1);
            float th0 = tA0 + tB0;
            float th1 = tA1 + tB1;

            float P0 = __cosf(th0 + qadd0);
            float P1 = __cosf(th1 + qadd1);

            // inclusive prefix product over the 8 wires (DPP scan)
            float s;
            s = dppf<0x111>(P0); P0 *= (w >= 1) ? s : 1.0f;
            s = dppf<0x111>(P1); P1 *= (w >= 1) ? s : 1.0f;
            s = dppf<0x112>(P0); P0 *= (w >= 2) ? s : 1.0f;
            s = dppf<0x112>(P1); P1 *= (w >= 2) ? s : 1.0f;
            s = dppf<0x114>(P0); P0 *= (w >= 4) ? s : 1.0f;
            s = dppf<0x114>(P1); P1 *= (w >= 4) ? s : 1.0f;

            float act0 = ascl * sigm_f(ascl * (mult0 * P0)) + aoff;
            float act1 = sigm_f(mult1 * P1);

            // swap gate-pairs across octets (same wire): row_ror:8
            float ex0 = dppf<0x128>(act0);
            float ex1 = dppf<0x128>(act1);
            float fv = gpr ? ex0  : act0;
            float iv = gpr ? ex1  : act1;
            float gv = gpr ? act0 : ex0;
            float ov = gpr ? act1 : ex1;

            cxw = fv*cxw + iv*gv;
            hxw = ov * tanh_f(cxw);

            if (gpr == 0 && bb_ < B) out[((long)t*B + bb_)*8 + w] = hxw;

            // hx all-gather: hxr[k] = hx_{(w-k)&7} via row_ror:k
            hxr[0] = hxw;
            hxr[1] = dppf<0x121>(hxw);
            hxr[2] = dppf<0x122>(hxw);
            hxr[3] = dppf<0x123>(hxw);
            hxr[4] = dppf<0x124>(hxw);
            hxr[5] = dppf<0x125>(hxw);
            hxr[6] = dppf<0x126>(hxw);
            hxr[7] = dppf<0x127>(hxw);
        }
    };

    // ---- chunk pipeline ----
    const int nch = (S + TCH - 1) / TCH;
    for (int c = 0; c < nch; ++c) {
        // stage x chunk c: 4 batches x TCH t x IDD floats (coalesced float4)
        {
            const int nf4 = 4 * TCH * (IDD/4);      // 1024 for IDD=64
            for (int idx = tid; idx < nf4; idx += 576) {
                int k4 = idx % (IDD/4);
                int r  = idx / (IDD/4);             // bs*TCH + tl
                int bs = r / TCH;
                int tl = r % TCH;
                int t  = c*TCH + tl; if (t >= S) t = S - 1;
                long bb = b0 + bs; if (bb >= B) bb = B - 1;
                float4 v = ((const float4*)(x_ + ((long)t*B + bb)*IDD))[k4];
                ((float4*)&xs[bs][tl][0])[k4] = v;
            }
        }
        __syncthreads();                            // xs chunk c ready

        if (tid < 512) {
            // GEMM chunk c: each thread 4 timesteps for its (b4, l)
            #pragma unroll
            for (int i = 0; i < TCH/4; ++i) {
                int t = c*TCH + sub*(TCH/4) + i;
                if (t < S) {
                    const float4* xv = (const float4*)&xs[b4g][t - c*TCH][0];
                    float a0 = bias, a1 = 0.0f, a2 = 0.0f, a3 = 0.0f;
                    #pragma unroll
                    for (int k4 = 0; k4 < IDD/4; ++k4) {
                        float4 v = xv[k4];           // broadcast within half
                        a0 = fmaf(wr[4*k4],   v.x, a0);
                        a1 = fmaf(wr[4*k4+1], v.y, a1);
                        a2 = fmaf(wr[4*k4+2], v.z, a2);
                        a3 = fmaf(wr[4*k4+3], v.w, a3);
                    }
                    ps[t][b4g][l] = (a0 + a1) + (a2 + a3);
                }
            }
        } else if (c > 0) {
            // recurrence over chunk c-1 (ps completed before prev barrier)
            int t0e = (c - 1) * TCH;
            int t1e = c * TCH; if (t1e > S) t1e = S;
            rec_run(t0e, t1e);
        }
        __syncthreads();                            // ps chunk c ready; xs free
    }

    // tail: recurrence over the last chunk
    if (tid >= 512) {
        int t0e = (nch - 1) * TCH;
        if (t0e < S) rec_run(t0e, S);
        if (gpr == 0 && bb_ < B) {
            out[((long)S*B + bb_)*8 + w]     = hxw;
            out[((long)S*B + B + bb_)*8 + w] = cxw;
        }
    }
}

// ---------------------------------------------------------------------------
// Specialized pre-GEMM (kept as fallback for S > 64), H == 8.
template<int IDD>
__global__ __launch_bounds__(256) void k_pre8(
    const float* __restrict__ x_,
    const float* __restrict__ W0, const float* __restrict__ b0p,
    const float* __restrict__ W1, const float* __restrict__ b1p,
    const float* __restrict__ W2, const float* __restrict__ b2p,
    const float* __restrict__ W3, const float* __restrict__ b3p,
    float* __restrict__ pre, int S, int B)
{
    constexpr int DIN = IDD + 8;
    __shared__ float xs[8][IDD];
    const int t   = blockIdx.x;
    const int tid = threadIdx.x;
    const int bl  = tid >> 5;
    const int l   = tid & 31;
    const int gp  = l >> 4, w = (l >> 1) & 7, e = l & 1;
    const int g   = 2*gp + e;
    const long b0 = (long)blockIdx.y * 8;
    const float* Wp[4] = {W0, W1, W2, W3};
    const float* bp[4] = {b0p, b1p, b2p, b3p};

    if (tid < 8*(IDD/4)) {
        int r = tid / (IDD/4), k4 = tid % (IDD/4);
        long bb = b0 + r; if (bb >= B) bb = B - 1;
        float4 v = ((const float4*)(x_ + ((long)t*B + bb)*IDD))[k4];
        ((float4*)&xs[r][0])[k4] = v;
    }

    float wr[IDD];
    {
        const float4* wv = (const float4*)(Wp[g] + (long)w*DIN);
        #pragma unroll
        for (int k4 = 0; k4 < IDD/4; ++k4) {
            float4 v = wv[k4];
            wr[4*k4] = v.x; wr[4*k4+1] = v.y; wr[4*k4+2] = v.z; wr[4*k4+3] = v.w;
        }
    }
    float a = bp[g][w];
    __syncthreads();

    const long b = b0 + bl;
    if (b >= B) return;
    const float4* xv = (const float4*)&xs[bl][0];
    #pragma unroll
    for (int k4 = 0; k4 < IDD/4; ++k4) {
        float4 v = xv[k4];
        a += wr[4*k4]*v.x + wr[4*k4+1]*v.y + wr[4*k4+2]*v.z + wr[4*k4+3]*v.w;
    }
    pre[((long)t*B + b)*32 + l] = a;
}

// ---------------------------------------------------------------------------
// Generic pre-GEMM fallback (runtime ID/H), f32 inputs, OLD layout
__global__ __launch_bounds__(256) void k_pre_gen(
    const float* __restrict__ x_,
    const float* W0, const float* b0p,
    const float* W1, const float* b1p,
    const float* W2, const float* b2p,
    const float* W3, const float* b3p,
    float* __restrict__ pre,
    int S, int B, int ID, int H, int SP)
{
    extern __shared__ float lds[];
    const int dIn  = ID + H;
    const int dInP = dIn + 1;
    float* xs    = lds;
    float* wsh   = lds + 64*SP;
    float* sbias = wsh + 4*H*dInP;
    const int t   = blockIdx.x;
    const int tid = threadIdx.x;
    const int bl  = tid & 63;
    const int q   = tid >> 6;
    const int b0  = blockIdx.y * 64;
    const float* Wp[4] = {W0, W1, W2, W3};
    const float* bp[4] = {b0p, b1p, b2p, b3p};

    for (int g = 0; g < 4; ++g)
        for (int idx = tid; idx < H*dIn; idx += 256) {
            int w = idx / dIn, k = idx - w*dIn;
            wsh[(g*H + w)*dInP + k] = Wp[g][idx];
        }
    for (int idx = tid; idx < 4*H; idx += 256)
        sbias[idx] = bp[idx / H][idx % H];

    {
        int total = 64 * ID;
        for (int i = tid; i < total; i += 256) {
            int r = i / ID, c = i - r*ID;
            long bb = (long)b0 + r; if (bb >= B) bb = B - 1;
            xs[r*SP + c] = x_[((long)t*B + bb)*ID + c];
        }
    }
    __syncthreads();

    const int b = b0 + bl;
    if (b < B) {
        const float* xrow = &xs[bl*SP];
        float* orow = pre + (((long)t*B + b)*4 + q)*H;
        for (int w = 0; w < H; ++w) {
            float acc = sbias[q*H + w];
            const float* wrow = &wsh[(q*H + w)*dInP];
            for (int k = 0; k < ID; ++k) acc += xrow[k] * wrow[k];
            orow[w] = acc;
        }
    }
}

// ---------------------------------------------------------------------------
// Recurrence, H==8/ID==64 fast path (fallback for S > 64).
__global__ __launch_bounds__(64) void k_rec8(
    const float* __restrict__ W0, const float* __restrict__ q0,
    const float* __restrict__ W1, const float* __restrict__ q1,
    const float* __restrict__ W2, const float* __restrict__ q2,
    const float* __restrict__ W3, const float* __restrict__ q3,
    const float* __restrict__ pre,
    float* __restrict__ out, int S, int B, int ID)
{
    const int dIn  = ID + 8;
    const int lane = threadIdx.x;
    const int w    = lane & 7;
    const int gp   = (lane >> 3) & 1;
    const int b    = blockIdx.x*4 + (lane >> 4);
    const int bs   = (b < B) ? b : (B - 1);
    const float* Wp[4] = {W0, W1, W2, W3};
    const float* qp[4] = {q0, q1, q2, q3};
    const int g0 = 2*gp, g1 = 2*gp + 1;

    float wrot0[8], wrot1[8];
    #pragma unroll
    for (int k = 0; k < 8; ++k) {
        int j = (w - k) & 7;
        wrot0[k] = Wp[g0][(long)w*dIn + ID + j];
        wrot1[k] = Wp[g1][(long)w*dIn + ID + j];
    }
    const float qv0 = qp[g0][w], qv1 = qp[g1][w];
    const float mult0 = (w < 7) ? __cosf(qv0) : 1.0f;
    const float mult1 = (w < 7) ? __cosf(qv1) : 1.0f;
    const float qadd0 = (w == 7) ? qv0 : 0.0f;
    const float qadd1 = (w == 7) ? qv1 : 0.0f;
    const float ascl = gp ? 2.0f : 1.0f;
    const float aoff = gp ? -1.0f : 0.0f;

    float cxw = 0.0f, hxw = 0.0f;
    float hxr[8];
    #pragma unroll
    for (int k = 0; k < 8; ++k) hxr[k] = 0.0f;

    const float2* base = (const float2*)(pre + (long)bs*32 + gp*16 + 2*w);
    const long tstep = (long)B*16;

    float2 pf[4];
    #pragma unroll
    for (int d = 0; d < 4; ++d) {
        int tt = (d < S) ? d : (S - 1);
        pf[d] = base[(long)tt*tstep];
    }

    for (int t0 = 0; t0 < S; t0 += 4) {
        #pragma unroll
        for (int d = 0; d < 4; ++d) {
            const int t = t0 + d;
            if (t < S) {
                float2 pc = pf[d];
                int tn = t + 4; if (tn >= S) tn = S - 1;
                pf[d] = base[(long)tn*tstep];

                float th0 = pc.x, th1 = pc.y;
                #pragma unroll
                for (int k = 0; k < 8; ++k) {
                    th0 = fmaf(wrot0[k], hxr[k], th0);
                    th1 = fmaf(wrot1[k], hxr[k], th1);
                }
                float P0 = __cosf(th0 + qadd0);
                float P1 = __cosf(th1 + qadd1);

                float s;
                s = dppf<0x111>(P0); P0 *= (w >= 1) ? s : 1.0f;
                s = dppf<0x111>(P1); P1 *= (w >= 1) ? s : 1.0f;
                s = dppf<0x112>(P0); P0 *= (w >= 2) ? s : 1.0f;
                s = dppf<0x112>(P1); P1 *= (w >= 2) ? s : 1.0f;
                s = dppf<0x114>(P0); P0 *= (w >= 4) ? s : 1.0f;
                s = dppf<0x114>(P1); P1 *= (w >= 4) ? s : 1.0f;

                float act0 = ascl * sigm_f(ascl * (mult0 * P0)) + aoff;
                float act1 = sigm_f(mult1 * P1);

                float ex0 = dppf<0x128>(act0);
                float ex1 = dppf<0x128>(act1);
                float fv = gp ? ex0  : act0;
                float iv = gp ? ex1  : act1;
                float gv = gp ? act0 : ex0;
                float ov = gp ? act1 : ex1;

                cxw = fv*cxw + iv*gv;
                hxw = ov * tanh_f(cxw);

                if (gp == 0 && b < B) out[((long)t*B + b)*8 + w] = hxw;

                hxr[0] = hxw;
                hxr[1] = dppf<0x121>(hxw);
                hxr[2] = dppf<0x122>(hxw);
                hxr[3] = dppf<0x123>(hxw);
                hxr[4] = dppf<0x124>(hxw);
                hxr[5] = dppf<0x125>(hxw);
                hxr[6] = dppf<0x126>(hxw);
                hxr[7] = dppf<0x127>(hxw);
            }
        }
    }

    if (gp == 0 && b < B) {
        out[((long)S*B + b)*8 + w]     = hxw;
        out[((long)S*B + B + b)*8 + w] = cxw;
    }
}

// ---------------------------------------------------------------------------
// Generic runtime-H recurrence fallback (H <= 32), f32, OLD pre layout.
__global__ __launch_bounds__(64) void k_rec_g(
    const float* __restrict__ pre,
    const float* W0, const float* q0,
    const float* W1, const float* q1,
    const float* W2, const float* q2,
    const float* W3, const float* q3,
    float* __restrict__ out, int S, int B, int ID, int H)
{
    __shared__ float sWh[4*32*32];
    __shared__ float scq[4*32];
    const int dIn = ID + H;
    const int tid = threadIdx.x;
    const int b   = blockIdx.x*64 + tid;
    const float* Wp[4] = {W0, W1, W2, W3};
    const float* qp[4] = {q0, q1, q2, q3};

    for (int idx = tid; idx < 4*H*H; idx += 64) {
        int g = idx / (H*H), r = idx % (H*H);
        int w = r / H, j = r % H;
        sWh[(g*H + w)*H + j] = Wp[g][(long)w*dIn + ID + j];
    }
    for (int idx = tid; idx < 4*H; idx += 64) {
        int g = idx / H, w = idx % H;
        float qv = qp[g][w];
        scq[idx] = (w < H-1) ? __cosf(qv) : qv;
    }
    __syncthreads();
    if (b >= B) return;

    float hx[32], cx[32], gate[4][32], th[32];
    for (int w = 0; w < H; ++w) { hx[w] = 0.0f; cx[w] = 0.0f; }

    for (int t = 0; t < S; ++t) {
        const float* pt = pre + ((long)t*B + b)*4*H;
        for (int g = 0; g < 4; ++g) {
            for (int w = 0; w < H; ++w) {
                float a = pt[g*H + w];
                const float* wrp = &sWh[(g*H + w)*H];
                for (int j = 0; j < H; ++j) a += wrp[j]*hx[j];
                th[w] = a;
            }
            float cum = 1.0f;
            for (int w = 0; w < H-1; ++w) {
                cum *= __cosf(th[w]);
                gate[g][w] = scq[g*H + w] * cum;
            }
            gate[g][H-1] = cum * __cosf(th[H-1] + scq[g*H + H-1]);
        }
        float* orow = out + ((long)t*B + b)*H;
        for (int w = 0; w < H; ++w) {
            float fv = sigm (gate[0][w]);
            float iv = sigm (gate[1][w]);
            float gv = tanh_(gate[2][w]);
            float ov = sigm (gate[3][w]);
            cx[w] = fv*cx[w] + iv*gv;
            hx[w] = ov*tanh_(cx[w]);
            orow[w] = hx[w];
        }
    }
    float* oh = out + ((long)S*B + b)*H;
    float* oc = out + ((long)S*B + B + b)*H;
    for (int w = 0; w < H; ++w) { oh[w] = hx[w]; oc[w] = cx[w]; }
}

static bool derive(long sz[13], long osz, long& S, long& B, long& ID, long& H) {
    H = sz[3];
    long dIn = (H > 0) ? sz[1] / H : 0;
    ID = dIn - H;
    long TB = (ID > 0) ? sz[0] / ID : 0;
    B = (H > 0) ? (osz / H - TB) / 2 : 0;
    S = (B > 0) ? TB / B : 0;
    return (H >= 1 && H <= 32 && ID >= 1 && B >= 1 && S >= 1 &&
            S*B == TB && (S*B + 2*B)*H == osz &&
            dIn*H == sz[1] && TB*ID == sz[0]);
}

extern "C" void kernel_launch(void* const* d_in, const int* in_sizes, int n_in,
                              void* d_out, int out_size, void* d_ws, size_t ws_size,
                              hipStream_t stream) {
    const float* x  = (const float*)d_in[0];
    const float* Wf = (const float*)d_in[1];  const float* bfv = (const float*)d_in[2];  const float* qf = (const float*)d_in[3];
    const float* Wi = (const float*)d_in[4];  const float* biv = (const float*)d_in[5];  const float* qi = (const float*)d_in[6];
    const float* Wg = (const float*)d_in[7];  const float* bgv = (const float*)d_in[8];  const float* qg = (const float*)d_in[9];
    const float* Wo = (const float*)d_in[10]; const float* bov = (const float*)d_in[11]; const float* qo = (const float*)d_in[12];
    float* out = (float*)d_out;

    long S = 0, B = 0, ID = 0, H = 0;
    bool ok = false;
    for (int scale : {1, 4, 2}) {
        long sz[13];
        for (int i = 0; i < 13; ++i) sz[i] = (long)in_sizes[i] / scale;
        long osz = (long)out_size / scale;
        if (derive(sz, osz, S, B, ID, H)) { ok = true; break; }
    }
    if (!ok) { H = 8; ID = 64; B = 256; S = 64; }
    long dIn = ID + H;

    if (H == 8 && ID == 64 && S <= 64) {
        // fully fused: single dispatch, GEMM overlapped with recurrence
        k_fused8<64><<<dim3((unsigned)((B + 3) / 4)), dim3(576), 0, stream>>>(
            x, Wf, bfv, qf, Wi, biv, qi, Wg, bgv, qg, Wo, bov, qo,
            out, (int)S, (int)B);
        return;
    }

    size_t pre_bytes = (size_t)S * 4 * H * B * sizeof(float);
    float* pre = (ws_size >= pre_bytes) ? (float*)d_ws : g_pre_static;

    if (H == 8 && ID == 64) {
        k_pre8<64><<<dim3((unsigned)S, (unsigned)((B + 7) / 8)), dim3(256), 0, stream>>>(
            x, Wf, bfv, Wi, biv, Wg, bgv, Wo, bov, pre, (int)S, (int)B);
        k_rec8<<<dim3((unsigned)((B + 3) / 4)), dim3(64), 0, stream>>>(
            Wf, qf, Wi, qi, Wg, qg, Wo, qo, pre, out, (int)S, (int)B, (int)ID);
    } else {
        int SP = (int)ID + 1;
        size_t lds_bytes = (size_t)(64*SP + 4*H*(dIn + 1) + 4*H) * sizeof(float);
        k_pre_gen<<<dim3((unsigned)S, (unsigned)((B + 63) / 64)), dim3(256), lds_bytes, stream>>>(
            x, Wf, bfv, Wi, biv, Wg, bgv, Wo, bov, pre,
            (int)S, (int)B, (int)ID, (int)H, SP);
        k_rec_g<<<dim3((unsigned)((B + 63) / 64)), dim3(64), 0, stream>>>(
            pre, Wf, qf, Wi, qi, Wg, qg, Wo, qo, out, (int)S, (int)B, (int)ID, (int)H);
    }
}

// Round 3
// 99.516 us; speedup vs baseline: 1.0446x; 1.0082x over previous
//
#include <hip/hip_runtime.h>
#include <hip/hip_bf16.h>

__device__ float g_pre_static[8 * 1024 * 1024];  // fallback scratch (32 MB)

__device__ __forceinline__ float rcp_(float x)   { return __builtin_amdgcn_rcpf(x); }
__device__ __forceinline__ float sigm_f(float x) { return rcp_(1.0f + __expf(-x)); }
__device__ __forceinline__ float tanh_f(float x) { return 1.0f - 2.0f*rcp_(__expf(2.0f*x) + 1.0f); }
__device__ __forceinline__ float sigm(float x)  { return 1.0f/(1.0f + __expf(-x)); }
__device__ __forceinline__ float tanh_(float x) { float e = __expf(2.0f*x); return (e-1.0f)/(e+1.0f); }

// DPP move within 16-lane rows: pure VALU, no lgkmcnt wait (vs ds_bpermute).
// SEMANTICS (verified R11/R12): row_shr:k / row_ror:k deliver to lane i the
// value from lane i-k (mod 16 for ror) — data moves toward HIGHER lanes.
template<int CTRL>
__device__ __forceinline__ float dppf(float x) {
    return __int_as_float(__builtin_amdgcn_update_dpp(
        0, __float_as_int(x), CTRL, 0xF, 0xF, true));
}
// CTRL: row_shr:k = 0x110+k ; row_ror:k = 0x120+k

// ---------------------------------------------------------------------------
// FUSED kernel, H == 8, ID == 64 (compile-time), S <= 64.
// One block per 4 batches, 576 threads (9 waves).
//   waves 0..7 : pre-GEMM chunk c into ps[t][b4][32]
//   wave  8    : validated DPP recurrence, lagging ONE chunk behind.
// NEW (R3): async-STAGE split — chunk c+1's x loads are issued to REGISTERS
// before the compute phase of chunk c and written to LDS after the barrier,
// so the ~900cy HBM latency hides under the ~2000cy GEMM/rec phase instead
// of sitting on the critical path once per chunk.
template<int IDD>
__global__ __launch_bounds__(576) void k_fused8(
    const float* __restrict__ x_,
    const float* __restrict__ W0, const float* __restrict__ b0p, const float* __restrict__ q0v,
    const float* __restrict__ W1, const float* __restrict__ b1p, const float* __restrict__ q1v,
    const float* __restrict__ W2, const float* __restrict__ b2p, const float* __restrict__ q2v,
    const float* __restrict__ W3, const float* __restrict__ b3p, const float* __restrict__ q3v,
    float* __restrict__ out, int S, int B)
{
    constexpr int DIN  = IDD + 8;
    constexpr int SMAX = 64;
    constexpr int TCH  = 16;                 // t-chunk (4 chunks for S=64)
    constexpr int NF4  = 4 * TCH * (IDD/4);  // float4 loads per chunk (1024)
    __shared__ float xs[4][TCH][IDD];        // 16 KB
    __shared__ float ps[SMAX][4][32];        // 32 KB  (pre, interleaved cols)

    const int tid = threadIdx.x;
    const long b0 = (long)blockIdx.x * 4;
    const float* Wp[4] = {W0, W1, W2, W3};
    const float* bp[4] = {b0p, b1p, b2p, b3p};
    const float* qp[4] = {q0v, q1v, q2v, q3v};

    // ---- GEMM identity (threads 0..511) ----
    const int l   = tid & 31;                // interleaved output column
    const int b4g = (tid >> 5) & 3;          // local batch
    const int sub = (tid >> 7) & 3;          // t-subrange within chunk
    const int gp  = l >> 4, w8 = (l >> 1) & 7, e = l & 1;
    const int g   = 2*gp + e;

    float wr[IDD];
    float bias = 0.0f;
    if (tid < 512) {                          // W row into registers (L1-hot)
        const float4* wv = (const float4*)(Wp[g] + (long)w8*DIN);
        #pragma unroll
        for (int k4 = 0; k4 < IDD/4; ++k4) {
            float4 v = wv[k4];
            wr[4*k4] = v.x; wr[4*k4+1] = v.y; wr[4*k4+2] = v.z; wr[4*k4+3] = v.w;
        }
        bias = bp[g][w8];
    }

    // ---- recurrence identity (threads 512..575, one wave) ----
    const int lane = tid & 63;
    const int w    = lane & 7;
    const int gpr  = (lane >> 3) & 1;
    const long bb_ = b0 + (lane >> 4);
    const int g0 = 2*gpr, g1 = 2*gpr + 1;

    float wrot0[8], wrot1[8];
    float mult0 = 1.0f, mult1 = 1.0f, qadd0 = 0.0f, qadd1 = 0.0f;
    if (tid >= 512) {
        #pragma unroll
        for (int k = 0; k < 8; ++k) {        // rotated rows match ror:k gather
            int j = (w - k) & 7;
            wrot0[k] = Wp[g0][(long)w*DIN + IDD + j];
            wrot1[k] = Wp[g1][(long)w*DIN + IDD + j];
        }
        float qv0 = qp[g0][w], qv1 = qp[g1][w];
        mult0 = (w < 7) ? __cosf(qv0) : 1.0f;
        mult1 = (w < 7) ? __cosf(qv1) : 1.0f;
        qadd0 = (w == 7) ? qv0 : 0.0f;
        qadd1 = (w == 7) ? qv1 : 0.0f;
    }
    const float ascl = gpr ? 2.0f : 1.0f;    // gate 2: tanh = 2*sigm(2x)-1
    const float aoff = gpr ? -1.0f : 0.0f;

    float cxw = 0.0f, hxw = 0.0f;
    float hxr[8];
    #pragma unroll
    for (int k = 0; k < 8; ++k) hxr[k] = 0.0f;

    // LDS float2 base: ps[t][b4][gpr*16 + 2w]; stride 64 float2 per t
    const float2* pbase = (const float2*)(&ps[0][lane >> 4][gpr*16 + 2*w]);

    // recurrence over [t0e, t1e) — prefetch clamped inside the range
    auto rec_run = [&](int t0e, int t1e) {
        float2 pn = pbase[(long)t0e * 64];
        for (int t = t0e; t < t1e; ++t) {
            float2 pc = pn;                  // loaded >= 1 chain ago
            int tn = (t + 1 < t1e) ? (t + 1) : t;
            pn = pbase[(long)tn * 64];       // issue next ds_read, no wait

            // th = pre + Wh.hx — two 4-deep chains + combine
            float tA0 = pc.x, tA1 = pc.y, tB0, tB1;
            tA0 = fmaf(wrot0[0], hxr[0], tA0);  tA1 = fmaf(wrot1[0], hxr[0], tA1);
            tA0 = fmaf(wrot0[1], hxr[1], tA0);  tA1 = fmaf(wrot1[1], hxr[1], tA1);
            tA0 = fmaf(wrot0[2], hxr[2], tA0);  tA1 = fmaf(wrot1[2], hxr[2], tA1);
            tA0 = fmaf(wrot0[3], hxr[3], tA0);  tA1 = fmaf(wrot1[3], hxr[3], tA1);
            tB0 = wrot0[4]*hxr[4];              tB1 = wrot1[4]*hxr[4];
            tB0 = fmaf(wrot0[5], hxr[5], tB0);  tB1 = fmaf(wrot1[5], hxr[5], tB1);
            tB0 = fmaf(wrot0[6], hxr[6], tB0);  tB1 = fmaf(wrot1[6], hxr[6], tB1);
            tB0 = fmaf(wrot0[7], hxr[7], tB0);  tB1 = fmaf(wrot1[7], hxr[7], tB1);
            float th0 = tA0 + tB0;
            float th1 = tA1 + tB1;

            float P0 = __cosf(th0 + qadd0);
            float P1 = __cosf(th1 + qadd1);

            // inclusive prefix product over the 8 wires (DPP scan)
            float s;
            s = dppf<0x111>(P0); P0 *= (w >= 1) ? s : 1.0f;
            s = dppf<0x111>(P1); P1 *= (w >= 1) ? s : 1.0f;
            s = dppf<0x112>(P0); P0 *= (w >= 2) ? s : 1.0f;
            s = dppf<0x112>(P1); P1 *= (w >= 2) ? s : 1.0f;
            s = dppf<0x114>(P0); P0 *= (w >= 4) ? s : 1.0f;
            s = dppf<0x114>(P1); P1 *= (w >= 4) ? s : 1.0f;

            float act0 = ascl * sigm_f(ascl * (mult0 * P0)) + aoff;
            float act1 = sigm_f(mult1 * P1);

            // swap gate-pairs across octets (same wire): row_ror:8
            float ex0 = dppf<0x128>(act0);
            float ex1 = dppf<0x128>(act1);
            float fv = gpr ? ex0  : act0;
            float iv = gpr ? ex1  : act1;
            float gv = gpr ? act0 : ex0;
            float ov = gpr ? act1 : ex1;

            cxw = fv*cxw + iv*gv;
            hxw = ov * tanh_f(cxw);

            if (gpr == 0 && bb_ < B) out[((long)t*B + bb_)*8 + w] = hxw;

            // hx all-gather: hxr[k] = hx_{(w-k)&7} via row_ror:k
            hxr[0] = hxw;
            hxr[1] = dppf<0x121>(hxw);
            hxr[2] = dppf<0x122>(hxw);
            hxr[3] = dppf<0x123>(hxw);
            hxr[4] = dppf<0x124>(hxw);
            hxr[5] = dppf<0x125>(hxw);
            hxr[6] = dppf<0x126>(hxw);
            hxr[7] = dppf<0x127>(hxw);
        }
    };

    // global-load address for staging index idx (chunk c), clamped
    auto xaddr = [&](int c, int idx) -> const float4* {
        int k4 = idx % (IDD/4);
        int r  = idx / (IDD/4);              // bs*TCH + tl
        int bs = r / TCH;
        int tl = r % TCH;
        int t  = c*TCH + tl; if (t >= S) t = S - 1;
        long bb = b0 + bs; if (bb >= B) bb = B - 1;
        return ((const float4*)(x_ + ((long)t*B + bb)*IDD)) + k4;
    };
    auto xdst = [&](int idx) -> float4* {
        int k4 = idx % (IDD/4);
        int r  = idx / (IDD/4);
        int bs = r / TCH;
        int tl = r % TCH;
        return ((float4*)&xs[bs][tl][0]) + k4;
    };

    // ---- prologue: stage chunk 0 directly ----
    {
        for (int idx = tid; idx < NF4; idx += 576)
            *xdst(idx) = *xaddr(0, idx);
    }
    __syncthreads();                          // xs chunk 0 ready

    // ---- chunk pipeline (async-stage split) ----
    const int nch = (S + TCH - 1) / TCH;
    for (int c = 0; c < nch; ++c) {
        const bool have_next = (c + 1 < nch);

        // issue chunk c+1 loads into registers (latency hides under compute)
        float4 r0, r1;
        const bool l0 = have_next;                       // tid < 1024 always
        const bool l1 = have_next && (tid + 576 < NF4);
        if (l0) r0 = *xaddr(c + 1, tid);
        if (l1) r1 = *xaddr(c + 1, tid + 576);

        if (tid < 512) {
            // GEMM chunk c: each thread 4 timesteps for its (b4, l)
            #pragma unroll
            for (int i = 0; i < TCH/4; ++i) {
                int t = c*TCH + sub*(TCH/4) + i;
                if (t < S) {
                    const float4* xv = (const float4*)&xs[b4g][t - c*TCH][0];
                    float a0 = bias, a1 = 0.0f, a2 = 0.0f, a3 = 0.0f;
                    #pragma unroll
                    for (int k4 = 0; k4 < IDD/4; ++k4) {
                        float4 v = xv[k4];           // broadcast within half
                        a0 = fmaf(wr[4*k4],   v.x, a0);
                        a1 = fmaf(wr[4*k4+1], v.y, a1);
                        a2 = fmaf(wr[4*k4+2], v.z, a2);
                        a3 = fmaf(wr[4*k4+3], v.w, a3);
                    }
                    ps[t][b4g][l] = (a0 + a1) + (a2 + a3);
                }
            }
        } else if (c > 0) {
            // recurrence over chunk c-1 (ps completed before prev barrier)
            int t0e = (c - 1) * TCH;
            int t1e = c * TCH; if (t1e > S) t1e = S;
            rec_run(t0e, t1e);
        }
        __syncthreads();              // xs chunk c consumed; ps chunk c done

        if (have_next) {
            // write staged registers to LDS (vmcnt wait ~free by now)
            if (l0) *xdst(tid) = r0;
            if (l1) *xdst(tid + 576) = r1;
            __syncthreads();          // xs chunk c+1 ready
        }
    }

    // tail: recurrence over the last chunk
    if (tid >= 512) {
        int t0e = (nch - 1) * TCH;
        if (t0e < S) rec_run(t0e, S);
        if (gpr == 0 && bb_ < B) {
            out[((long)S*B + bb_)*8 + w]     = hxw;
            out[((long)S*B + B + bb_)*8 + w] = cxw;
        }
    }
}

// ---------------------------------------------------------------------------
// Specialized pre-GEMM (kept as fallback for S > 64), H == 8.
template<int IDD>
__global__ __launch_bounds__(256) void k_pre8(
    const float* __restrict__ x_,
    const float* __restrict__ W0, const float* __restrict__ b0p,
    const float* __restrict__ W1, const float* __restrict__ b1p,
    const float* __restrict__ W2, const float* __restrict__ b2p,
    const float* __restrict__ W3, const float* __restrict__ b3p,
    float* __restrict__ pre, int S, int B)
{
    constexpr int DIN = IDD + 8;
    __shared__ float xs[8][IDD];
    const int t   = blockIdx.x;
    const int tid = threadIdx.x;
    const int bl  = tid >> 5;
    const int l   = tid & 31;
    const int gp  = l >> 4, w = (l >> 1) & 7, e = l & 1;
    const int g   = 2*gp + e;
    const long b0 = (long)blockIdx.y * 8;
    const float* Wp[4] = {W0, W1, W2, W3};
    const float* bp[4] = {b0p, b1p, b2p, b3p};

    if (tid < 8*(IDD/4)) {
        int r = tid / (IDD/4), k4 = tid % (IDD/4);
        long bb = b0 + r; if (bb >= B) bb = B - 1;
        float4 v = ((const float4*)(x_ + ((long)t*B + bb)*IDD))[k4];
        ((float4*)&xs[r][0])[k4] = v;
    }

    float wr[IDD];
    {
        const float4* wv = (const float4*)(Wp[g] + (long)w*DIN);
        #pragma unroll
        for (int k4 = 0; k4 < IDD/4; ++k4) {
            float4 v = wv[k4];
            wr[4*k4] = v.x; wr[4*k4+1] = v.y; wr[4*k4+2] = v.z; wr[4*k4+3] = v.w;
        }
    }
    float a = bp[g][w];
    __syncthreads();

    const long b = b0 + bl;
    if (b >= B) return;
    const float4* xv = (const float4*)&xs[bl][0];
    #pragma unroll
    for (int k4 = 0; k4 < IDD/4; ++k4) {
        float4 v = xv[k4];
        a += wr[4*k4]*v.x + wr[4*k4+1]*v.y + wr[4*k4+2]*v.z + wr[4*k4+3]*v.w;
    }
    pre[((long)t*B + b)*32 + l] = a;
}

// ---------------------------------------------------------------------------
// Generic pre-GEMM fallback (runtime ID/H), f32 inputs, OLD layout
__global__ __launch_bounds__(256) void k_pre_gen(
    const float* __restrict__ x_,
    const float* W0, const float* b0p,
    const float* W1, const float* b1p,
    const float* W2, const float* b2p,
    const float* W3, const float* b3p,
    float* __restrict__ pre,
    int S, int B, int ID, int H, int SP)
{
    extern __shared__ float lds[];
    const int dIn  = ID + H;
    const int dInP = dIn + 1;
    float* xs    = lds;
    float* wsh   = lds + 64*SP;
    float* sbias = wsh + 4*H*dInP;
    const int t   = blockIdx.x;
    const int tid = threadIdx.x;
    const int bl  = tid & 63;
    const int q   = tid >> 6;
    const int b0  = blockIdx.y * 64;
    const float* Wp[4] = {W0, W1, W2, W3};
    const float* bp[4] = {b0p, b1p, b2p, b3p};

    for (int g = 0; g < 4; ++g)
        for (int idx = tid; idx < H*dIn; idx += 256) {
            int w = idx / dIn, k = idx - w*dIn;
            wsh[(g*H + w)*dInP + k] = Wp[g][idx];
        }
    for (int idx = tid; idx < 4*H; idx += 256)
        sbias[idx] = bp[idx / H][idx % H];

    {
        int total = 64 * ID;
        for (int i = tid; i < total; i += 256) {
            int r = i / ID, c = i - r*ID;
            long bb = (long)b0 + r; if (bb >= B) bb = B - 1;
            xs[r*SP + c] = x_[((long)t*B + bb)*ID + c];
        }
    }
    __syncthreads();

    const int b = b0 + bl;
    if (b < B) {
        const float* xrow = &xs[bl*SP];
        float* orow = pre + (((long)t*B + b)*4 + q)*H;
        for (int w = 0; w < H; ++w) {
            float acc = sbias[q*H + w];
            const float* wrow = &wsh[(q*H + w)*dInP];
            for (int k = 0; k < ID; ++k) acc += xrow[k] * wrow[k];
            orow[w] = acc;
        }
    }
}

// ---------------------------------------------------------------------------
// Recurrence, H==8/ID==64 fast path (fallback for S > 64).
__global__ __launch_bounds__(64) void k_rec8(
    const float* __restrict__ W0, const float* __restrict__ q0,
    const float* __restrict__ W1, const float* __restrict__ q1,
    const float* __restrict__ W2, const float* __restrict__ q2,
    const float* __restrict__ W3, const float* __restrict__ q3,
    const float* __restrict__ pre,
    float* __restrict__ out, int S, int B, int ID)
{
    const int dIn  = ID + 8;
    const int lane = threadIdx.x;
    const int w    = lane & 7;
    const int gp   = (lane >> 3) & 1;
    const int b    = blockIdx.x*4 + (lane >> 4);
    const int bs   = (b < B) ? b : (B - 1);
    const float* Wp[4] = {W0, W1, W2, W3};
    const float* qp[4] = {q0, q1, q2, q3};
    const int g0 = 2*gp, g1 = 2*gp + 1;

    float wrot0[8], wrot1[8];
    #pragma unroll
    for (int k = 0; k < 8; ++k) {
        int j = (w - k) & 7;
        wrot0[k] = Wp[g0][(long)w*dIn + ID + j];
        wrot1[k] = Wp[g1][(long)w*dIn + ID + j];
    }
    const float qv0 = qp[g0][w], qv1 = qp[g1][w];
    const float mult0 = (w < 7) ? __cosf(qv0) : 1.0f;
    const float mult1 = (w < 7) ? __cosf(qv1) : 1.0f;
    const float qadd0 = (w == 7) ? qv0 : 0.0f;
    const float qadd1 = (w == 7) ? qv1 : 0.0f;
    const float ascl = gp ? 2.0f : 1.0f;
    const float aoff = gp ? -1.0f : 0.0f;

    float cxw = 0.0f, hxw = 0.0f;
    float hxr[8];
    #pragma unroll
    for (int k = 0; k < 8; ++k) hxr[k] = 0.0f;

    const float2* base = (const float2*)(pre + (long)bs*32 + gp*16 + 2*w);
    const long tstep = (long)B*16;

    float2 pf[4];
    #pragma unroll
    for (int d = 0; d < 4; ++d) {
        int tt = (d < S) ? d : (S - 1);
        pf[d] = base[(long)tt*tstep];
    }

    for (int t0 = 0; t0 < S; t0 += 4) {
        #pragma unroll
        for (int d = 0; d < 4; ++d) {
            const int t = t0 + d;
            if (t < S) {
                float2 pc = pf[d];
                int tn = t + 4; if (tn >= S) tn = S - 1;
                pf[d] = base[(long)tn*tstep];

                float th0 = pc.x, th1 = pc.y;
                #pragma unroll
                for (int k = 0; k < 8; ++k) {
                    th0 = fmaf(wrot0[k], hxr[k], th0);
                    th1 = fmaf(wrot1[k], hxr[k], th1);
                }
                float P0 = __cosf(th0 + qadd0);
                float P1 = __cosf(th1 + qadd1);

                float s;
                s = dppf<0x111>(P0); P0 *= (w >= 1) ? s : 1.0f;
                s = dppf<0x111>(P1); P1 *= (w >= 1) ? s : 1.0f;
                s = dppf<0x112>(P0); P0 *= (w >= 2) ? s : 1.0f;
                s = dppf<0x112>(P1); P1 *= (w >= 2) ? s : 1.0f;
                s = dppf<0x114>(P0); P0 *= (w >= 4) ? s : 1.0f;
                s = dppf<0x114>(P1); P1 *= (w >= 4) ? s : 1.0f;

                float act0 = ascl * sigm_f(ascl * (mult0 * P0)) + aoff;
                float act1 = sigm_f(mult1 * P1);

                float ex0 = dppf<0x128>(act0);
                float ex1 = dppf<0x128>(act1);
                float fv = gp ? ex0  : act0;
                float iv = gp ? ex1  : act1;
                float gv = gp ? act0 : ex0;
                float ov = gp ? act1 : ex1;

                cxw = fv*cxw + iv*gv;
                hxw = ov * tanh_f(cxw);

                if (gp == 0 && b < B) out[((long)t*B + b)*8 + w] = hxw;

                hxr[0] = hxw;
                hxr[1] = dppf<0x121>(hxw);
                hxr[2] = dppf<0x122>(hxw);
                hxr[3] = dppf<0x123>(hxw);
                hxr[4] = dppf<0x124>(hxw);
                hxr[5] = dppf<0x125>(hxw);
                hxr[6] = dppf<0x126>(hxw);
                hxr[7] = dppf<0x127>(hxw);
            }
        }
    }

    if (gp == 0 && b < B) {
        out[((long)S*B + b)*8 + w]     = hxw;
        out[((long)S*B + B + b)*8 + w] = cxw;
    }
}

// ---------------------------------------------------------------------------
// Generic runtime-H recurrence fallback (H <= 32), f32, OLD pre layout.
__global__ __launch_bounds__(64) void k_rec_g(
    const float* __restrict__ pre,
    const float* W0, const float* q0,
    const float* W1, const float* q1,
    const float* W2, const float* q2,
    const float* W3, const float* q3,
    float* __restrict__ out, int S, int B, int ID, int H)
{
    __shared__ float sWh[4*32*32];
    __shared__ float scq[4*32];
    const int dIn = ID + H;
    const int tid = threadIdx.x;
    const int b   = blockIdx.x*64 + tid;
    const float* Wp[4] = {W0, W1, W2, W3};
    const float* qp[4] = {q0, q1, q2, q3};

    for (int idx = tid; idx < 4*H*H; idx += 64) {
        int g = idx / (H*H), r = idx % (H*H);
        int w = r / H, j = r % H;
        sWh[(g*H + w)*H + j] = Wp[g][(long)w*dIn + ID + j];
    }
    for (int idx = tid; idx < 4*H; idx += 64) {
        int g = idx / H, w = idx % H;
        float qv = qp[g][w];
        scq[idx] = (w < H-1) ? __cosf(qv) : qv;
    }
    __syncthreads();
    if (b >= B) return;

    float hx[32], cx[32], gate[4][32], th[32];
    for (int w = 0; w < H; ++w) { hx[w] = 0.0f; cx[w] = 0.0f; }

    for (int t = 0; t < S; ++t) {
        const float* pt = pre + ((long)t*B + b)*4*H;
        for (int g = 0; g < 4; ++g) {
            for (int w = 0; w < H; ++w) {
                float a = pt[g*H + w];
                const float* wrp = &sWh[(g*H + w)*H];
                for (int j = 0; j < H; ++j) a += wrp[j]*hx[j];
                th[w] = a;
            }
            float cum = 1.0f;
            for (int w = 0; w < H-1; ++w) {
                cum *= __cosf(th[w]);
                gate[g][w] = scq[g*H + w] * cum;
            }
            gate[g][H-1] = cum * __cosf(th[H-1] + scq[g*H + H-1]);
        }
        float* orow = out + ((long)t*B + b)*H;
        for (int w = 0; w < H; ++w) {
            float fv = sigm (gate[0][w]);
            float iv = sigm (gate[1][w]);
            float gv = tanh_(gate[2][w]);
            float ov = sigm (gate[3][w]);
            cx[w] = fv*cx[w] + iv*gv;
            hx[w] = ov*tanh_(cx[w]);
            orow[w] = hx[w];
        }
    }
    float* oh = out + ((long)S*B + b)*H;
    float* oc = out + ((long)S*B + B + b)*H;
    for (int w = 0; w < H; ++w) { oh[w] = hx[w]; oc[w] = cx[w]; }
}

static bool derive(long sz[13], long osz, long& S, long& B, long& ID, long& H) {
    H = sz[3];
    long dIn = (H > 0) ? sz[1] / H : 0;
    ID = dIn - H;
    long TB = (ID > 0) ? sz[0] / ID : 0;
    B = (H > 0) ? (osz / H - TB) / 2 : 0;
    S = (B > 0) ? TB / B : 0;
    return (H >= 1 && H <= 32 && ID >= 1 && B >= 1 && S >= 1 &&
            S*B == TB && (S*B + 2*B)*H == osz &&
            dIn*H == sz[1] && TB*ID == sz[0]);
}

extern "C" void kernel_launch(void* const* d_in, const int* in_sizes, int n_in,
                              void* d_out, int out_size, void* d_ws, size_t ws_size,
                              hipStream_t stream) {
    const float* x  = (const float*)d_in[0];
    const float* Wf = (const float*)d_in[1];  const float* bfv = (const float*)d_in[2];  const float* qf = (const float*)d_in[3];
    const float* Wi = (const float*)d_in[4];  const float* biv = (const float*)d_in[5];  const float* qi = (const float*)d_in[6];
    const float* Wg = (const float*)d_in[7];  const float* bgv = (const float*)d_in[8];  const float* qg = (const float*)d_in[9];
    const float* Wo = (const float*)d_in[10]; const float* bov = (const float*)d_in[11]; const float* qo = (const float*)d_in[12];
    float* out = (float*)d_out;

    long S = 0, B = 0, ID = 0, H = 0;
    bool ok = false;
    for (int scale : {1, 4, 2}) {
        long sz[13];
        for (int i = 0; i < 13; ++i) sz[i] = (long)in_sizes[i] / scale;
        long osz = (long)out_size / scale;
        if (derive(sz, osz, S, B, ID, H)) { ok = true; break; }
    }
    if (!ok) { H = 8; ID = 64; B = 256; S = 64; }
    long dIn = ID + H;

    if (H == 8 && ID == 64 && S <= 64) {
        // fully fused: single dispatch, GEMM overlapped with recurrence,
        // async-staged x (HBM latency hidden under compute)
        k_fused8<64><<<dim3((unsigned)((B + 3) / 4)), dim3(576), 0, stream>>>(
            x, Wf, bfv, qf, Wi, biv, qi, Wg, bgv, qg, Wo, bov, qo,
            out, (int)S, (int)B);
        return;
    }

    size_t pre_bytes = (size_t)S * 4 * H * B * sizeof(float);
    float* pre = (ws_size >= pre_bytes) ? (float*)d_ws : g_pre_static;

    if (H == 8 && ID == 64) {
        k_pre8<64><<<dim3((unsigned)S, (unsigned)((B + 7) / 8)), dim3(256), 0, stream>>>(
            x, Wf, bfv, Wi, biv, Wg, bgv, Wo, bov, pre, (int)S, (int)B);
        k_rec8<<<dim3((unsigned)((B + 3) / 4)), dim3(64), 0, stream>>>(
            Wf, qf, Wi, qi, Wg, qg, Wo, qo, pre, out, (int)S, (int)B, (int)ID);
    } else {
        int SP = (int)ID + 1;
        size_t lds_bytes = (size_t)(64*SP + 4*H*(dIn + 1) + 4*H) * sizeof(float);
        k_pre_gen<<<dim3((unsigned)S, (unsigned)((B + 63) / 64)), dim3(256), lds_bytes, stream>>>(
            x, Wf, bfv, Wi, biv, Wg, bgv, Wo, bov, pre,
            (int)S, (int)B, (int)ID, (int)H, SP);
        k_rec_g<<<dim3((unsigned)((B + 63) / 64)), dim3(64), 0, stream>>>(
            pre, Wf, qf, Wi, qi, Wg, qg, Wo, qo, out, (int)S, (int)B, (int)ID, (int)H);
    }
}